// Round 3
// baseline (282.054 us; speedup 1.0000x reference)
//
#include <hip/hip_runtime.h>
#include <cstdint>
#include <cstddef>

typedef unsigned short u16;
typedef unsigned int u32;
typedef __attribute__((ext_vector_type(4))) float f32x4;
typedef __attribute__((ext_vector_type(8))) short s16x8;

__device__ __forceinline__ u16 f2bf(float f) {
  u32 u = __float_as_uint(f);
  u = (u + 0x7fffu + ((u >> 16) & 1u)) >> 16;
  return (u16)u;
}

__device__ __forceinline__ float silu_f(float y) {
  return y / (1.0f + __expf(-y));
}

// ---------------------------------------------------------------------------
// Weight quantization: ONE WAVE per output channel, 4 channels per block.
// Exact median of |w| via 8-bit radix select on abs bit pattern.
// ---------------------------------------------------------------------------
template<int N, int REMAP>
__global__ __launch_bounds__(256) void quant_kernel(
    const float* __restrict__ w, const float* __restrict__ bias,
    const float* __restrict__ g, const float* __restrict__ be,
    const float* __restrict__ mu, const float* __restrict__ var,
    u16* __restrict__ wq, float* __restrict__ alpha, float* __restrict__ beta)
{
  constexpr int NV = N / 64;
  __shared__ int hist[4 * 256];

  const int tid = threadIdx.x;
  const int wave = tid >> 6;
  const int lane = tid & 63;
  const int ch = blockIdx.x * 4 + wave;
  const int wb = wave * 256;

  u32 vals[NV];
  const float* wp = w + (size_t)ch * N;
  #pragma unroll
  for (int t = 0; t < NV; ++t)
    vals[t] = __float_as_uint(wp[lane + 64 * t]);

  const int r0 = N / 2;
  int r = r0;
  u32 prefix = 0;
  #pragma unroll
  for (int pass = 0; pass < 4; ++pass) {
    const int shift = 24 - 8 * pass;
    hist[wb + lane] = 0;
    hist[wb + 64 + lane] = 0;
    hist[wb + 128 + lane] = 0;
    hist[wb + 192 + lane] = 0;
    __syncthreads();
    #pragma unroll
    for (int t = 0; t < NV; ++t) {
      u32 a = vals[t] & 0x7fffffffu;
      bool cand;
      if (pass == 0) cand = true;
      else cand = ((a >> (shift + 8)) == (prefix >> (shift + 8)));
      if (cand) atomicAdd(&hist[wb + ((a >> shift) & 255)], 1);
    }
    __syncthreads();
    int h0 = hist[wb + 4 * lane + 0];
    int h1 = hist[wb + 4 * lane + 1];
    int h2 = hist[wb + 4 * lane + 2];
    int h3 = hist[wb + 4 * lane + 3];
    int s4 = h0 + h1 + h2 + h3;
    int cum = s4;
    #pragma unroll
    for (int off = 1; off < 64; off <<= 1) {
      int tt = __shfl_up(cum, off);
      if (lane >= off) cum += tt;
    }
    int pre = cum - s4;
    bool sel = (r > pre) && (r <= cum);
    unsigned long long bal = __ballot(sel);
    int src = __ffsll((unsigned long long)bal) - 1;
    int c0 = pre + h0, c1 = c0 + h1, c2 = c1 + h2;
    int d_l, nr_l;
    if (r <= c0)      { d_l = 4 * lane + 0; nr_l = r - pre; }
    else if (r <= c1) { d_l = 4 * lane + 1; nr_l = r - c0; }
    else if (r <= c2) { d_l = 4 * lane + 2; nr_l = r - c1; }
    else              { d_l = 4 * lane + 3; nr_l = r - c2; }
    int d = __shfl(d_l, src);
    r = __shfl(nr_l, src);
    prefix |= (u32)d << shift;
    __syncthreads();
  }
  const u32 v0 = prefix;

  int cle = 0;
  u32 mn = 0xFFFFFFFFu;
  #pragma unroll
  for (int t = 0; t < NV; ++t) {
    u32 a = vals[t] & 0x7fffffffu;
    cle += (a <= v0) ? 1 : 0;
    if (a > v0) mn = min(mn, a);
  }
  #pragma unroll
  for (int off = 1; off < 64; off <<= 1) {
    cle += __shfl_xor(cle, off);
    mn = min(mn, (u32)__shfl_xor((int)mn, off));
  }
  u32 v1 = (cle >= r0 + 1) ? v0 : mn;

  float s = 0.5f * (__uint_as_float(v0) + __uint_as_float(v1));
  s = fmaxf(s, 1e-8f);

  #pragma unroll
  for (int t = 0; t < NV; ++t) {
    int i = lane + 64 * t;
    float q = rintf(__uint_as_float(vals[t]) / s);
    q = fminf(fmaxf(q, -1.0f), 1.0f);
    int oi;
    if (REMAP) {
      int cin = i / 9, tap = i - cin * 9;
      oi = tap * 256 + cin;
    } else {
      oi = i;
    }
    wq[(size_t)ch * N + oi] = f2bf(q);
  }
  if (lane == 0) {
    float sc = g[ch] / sqrtf(var[ch] + 1e-5f);
    alpha[ch] = s * sc;
    beta[ch] = (bias[ch] - mu[ch]) * sc + be[ch];
  }
}

// ---------------------------------------------------------------------------
// x (NCHW fp32) -> xb (NHWC bf16): [64][196][1024]
// ---------------------------------------------------------------------------
__global__ __launch_bounds__(256) void transpose_cast_kernel(
    const float* __restrict__ x, u16* __restrict__ xb)
{
  __shared__ u16 tile[64 * 198];
  const int n = blockIdx.x;
  const int c0 = blockIdx.y * 64;
  const float* xp = x + ((size_t)n * 1024 + c0) * 196;
  for (int i = threadIdx.x; i < 64 * 196; i += 256) {
    int c = i / 196, hw = i - c * 196;
    tile[c * 198 + hw] = f2bf(xp[i]);
  }
  __syncthreads();
  u16* op = xb + (size_t)n * 196 * 1024 + c0;
  for (int i = threadIdx.x; i < 64 * 196; i += 256) {
    int hw = i >> 6, c = i & 63;
    op[(size_t)hw * 1024 + c] = tile[c * 198 + hw];
  }
}

// ---------------------------------------------------------------------------
// GEMM: C[c][j] = sum_k W[c][k] * Act[j][k]. Tile: 128 channels x BJ pos,
// BK=64, mfma_f32_16x16x32_bf16, K-major operands, XOR-swizzled LDS.
// MODE 1: B = xb flat; store silu(bn) bf16 into padded act1p  (BJ=64)
// MODE 2: B gathered from act1p (implicit 3x3); store bf16 act2 (BJ=64)
// MODE 3: B = act2 flat; coalesced fp32 NCHW epilogue via LDS    (BJ=128)
// ---------------------------------------------------------------------------
template<int MODE, int KTOT, int BJ>
__global__ __launch_bounds__(256, 2) void gemm_kernel(
    const u16* __restrict__ Wq, const u16* __restrict__ Bact,
    const float* __restrict__ alpha, const float* __restrict__ beta,
    u16* __restrict__ outb, float* __restrict__ outf, const float* __restrict__ xres)
{
  constexpr int BK = 64;
  constexpr int NKT = KTOT / BK;
  constexpr int NI = BJ / 32;          // n-fragments per wave
  constexpr int SMEM_SIZE = (MODE == 3) ? 34816 : (16384 + BJ * BK * 2 + BJ * 4 + 1024);

  __shared__ __align__(16) char smem[SMEM_SIZE];
  u16* As = (u16*)smem;                                   // 128 x 64
  u16* Bs = (u16*)(smem + 16384);                         // BJ x 64
  int* rowbase = (int*)(smem + 16384 + BJ * BK * 2);      // MODE 2 only
  float* aS = (float*)(MODE == 3 ? (smem + 33792) : (smem + 16384 + BJ * BK * 2 + BJ * 4));
  float* bS = aS + 128;
  float* lbuf = (float*)smem;                             // MODE 3 epilogue, 64 x 132

  const int tid = threadIdx.x;
  const int jb = blockIdx.x * BJ;
  const int cb = blockIdx.y * 128;
  const int wave = tid >> 6;
  const int lane = tid & 63;
  const int wm = (wave & 1) * 64;
  const int wn = (wave >> 1) * (BJ / 2);
  const int quad = lane >> 4;
  const int l16 = lane & 15;

  if (tid < 128) {
    aS[tid] = alpha[cb + tid];
    bS[tid] = beta[cb + tid];
  }
  if (MODE == 2 && tid < BJ) {
    int j = jb + tid;
    int n = j / 196, hw = j - n * 196;
    int h = hw / 14, w = hw - h * 14;
    rowbase[tid] = ((n * 16 + h) * 16 + w) * 256;  // padded NHWC base, tap (0,0)
  }
  __syncthreads();

  f32x4 acc[4][NI];
  #pragma unroll
  for (int a = 0; a < 4; ++a)
    #pragma unroll
    for (int b = 0; b < NI; ++b)
      acc[a][b] = {0.f, 0.f, 0.f, 0.f};

  const int row_s = tid >> 3;   // staging row (0..31)
  const int cc_s = tid & 7;     // 16B chunk within BK row

  for (int kt = 0; kt < NKT; ++kt) {
    {   // stage A (weights)
      const uint4* gp = reinterpret_cast<const uint4*>(Wq + (size_t)cb * KTOT + kt * BK);
      #pragma unroll
      for (int i = 0; i < 4; ++i) {
        int row = row_s + 32 * i;
        uint4 v = gp[(size_t)row * (KTOT / 8) + cc_s];
        *reinterpret_cast<uint4*>(&As[row * BK + ((cc_s ^ (row & 7)) << 3)]) = v;
      }
    }
    if (MODE == 2) {   // implicit 3x3 gather
      int tap = kt >> 2;
      int c0 = (kt & 3) * 64;
      int dy = tap / 3, dx = tap - dy * 3;
      int tapoff = (dy * 16 + dx) * 256 + c0;
      const uint4* gp = reinterpret_cast<const uint4*>(Bact);
      #pragma unroll
      for (int i = 0; i < BJ / 32; ++i) {
        int row = row_s + 32 * i;
        uint4 v = gp[((rowbase[row] + tapoff) >> 3) + cc_s];
        *reinterpret_cast<uint4*>(&Bs[row * BK + ((cc_s ^ (row & 7)) << 3)]) = v;
      }
    } else {
      const uint4* gp = reinterpret_cast<const uint4*>(Bact + (size_t)jb * KTOT + kt * BK);
      #pragma unroll
      for (int i = 0; i < BJ / 32; ++i) {
        int row = row_s + 32 * i;
        uint4 v = gp[(size_t)row * (KTOT / 8) + cc_s];
        *reinterpret_cast<uint4*>(&Bs[row * BK + ((cc_s ^ (row & 7)) << 3)]) = v;
      }
    }
    __syncthreads();

    #pragma unroll
    for (int s = 0; s < 2; ++s) {
      s16x8 af[4], bf[NI];
      #pragma unroll
      for (int mi = 0; mi < 4; ++mi) {
        int row = wm + mi * 16 + l16;
        int kc = s * 4 + quad;
        af[mi] = *reinterpret_cast<const s16x8*>(&As[row * BK + ((kc ^ (row & 7)) << 3)]);
      }
      #pragma unroll
      for (int ni = 0; ni < NI; ++ni) {
        int row = wn + ni * 16 + l16;
        int kc = s * 4 + quad;
        bf[ni] = *reinterpret_cast<const s16x8*>(&Bs[row * BK + ((kc ^ (row & 7)) << 3)]);
      }
      #pragma unroll
      for (int mi = 0; mi < 4; ++mi)
        #pragma unroll
        for (int ni = 0; ni < NI; ++ni)
          acc[mi][ni] = __builtin_amdgcn_mfma_f32_16x16x32_bf16(af[mi], bf[ni], acc[mi][ni], 0, 0, 0);
    }
    __syncthreads();
  }

  // Epilogue. D layout: row(channel) = quad*4 + reg, col(j) = lane&15.
  if (MODE == 1 || MODE == 2) {
    #pragma unroll
    for (int mi = 0; mi < 4; ++mi) {
      const int lc = wm + mi * 16 + quad * 4;
      #pragma unroll
      for (int ni = 0; ni < NI; ++ni) {
        const int j = jb + wn + ni * 16 + l16;
        ushort4 pk;
        float y;
        y = silu_f(aS[lc + 0] * acc[mi][ni][0] + bS[lc + 0]); pk.x = f2bf(y);
        y = silu_f(aS[lc + 1] * acc[mi][ni][1] + bS[lc + 1]); pk.y = f2bf(y);
        y = silu_f(aS[lc + 2] * acc[mi][ni][2] + bS[lc + 2]); pk.z = f2bf(y);
        y = silu_f(aS[lc + 3] * acc[mi][ni][3] + bS[lc + 3]); pk.w = f2bf(y);
        size_t base;
        if (MODE == 1) {
          int n = j / 196, hw = j - n * 196;
          int h = hw / 14, w = hw - h * 14;
          base = (size_t)(((n * 16 + h + 1) * 16) + (w + 1)) * 256 + cb + lc;
        } else {
          base = (size_t)j * 256 + cb + lc;
        }
        *reinterpret_cast<ushort4*>(&outb[base]) = pk;
      }
    }
  } else {
    // MODE 3: two 64-channel chunks through LDS, fully coalesced fp32 out.
    #pragma unroll
    for (int k = 0; k < 2; ++k) {
      if ((wave & 1) == k) {
        #pragma unroll
        for (int mi = 0; mi < 4; ++mi) {
          const int cl = mi * 16 + quad * 4;        // 0..63 within chunk
          const int gc = 64 * k + cl;               // 0..127 within tile
          #pragma unroll
          for (int ni = 0; ni < 4; ++ni) {
            const int jj = wn + ni * 16 + l16;      // 0..127
            #pragma unroll
            for (int r = 0; r < 4; ++r)
              lbuf[(cl + r) * 132 + jj] = aS[gc + r] * acc[mi][ni][r] + bS[gc + r];
          }
        }
      }
      __syncthreads();
      #pragma unroll
      for (int it = 0; it < 8; ++it) {
        int idx = tid + it * 256;          // 0..2047
        int cl = idx >> 5;                 // 0..63
        int jg = idx & 31;                 // float4 group
        int c = cb + 64 * k + cl;
        int j0 = jb + jg * 4;
        int n = j0 / 196, hw = j0 - n * 196;
        size_t o = (size_t)n * 200704 + (size_t)c * 196 + hw;
        float4 lv = *reinterpret_cast<float4*>(&lbuf[cl * 132 + jg * 4]);
        float4 xv = *reinterpret_cast<const float4*>(&xres[o]);
        float4 ov;
        ov.x = silu_f(lv.x + xv.x);
        ov.y = silu_f(lv.y + xv.y);
        ov.z = silu_f(lv.z + xv.z);
        ov.w = silu_f(lv.w + xv.w);
        *reinterpret_cast<float4*>(&outf[o]) = ov;
      }
      __syncthreads();
    }
  }
}

// ---------------------------------------------------------------------------
extern "C" void kernel_launch(void* const* d_in, const int* in_sizes, int n_in,
                              void* d_out, int out_size, void* d_ws, size_t ws_size,
                              hipStream_t stream)
{
  const float* x   = (const float*)d_in[0];
  const float* w1  = (const float*)d_in[1];
  const float* b1  = (const float*)d_in[2];
  const float* g1  = (const float*)d_in[3];
  const float* be1 = (const float*)d_in[4];
  const float* m1  = (const float*)d_in[5];
  const float* v1  = (const float*)d_in[6];
  const float* w2  = (const float*)d_in[7];
  const float* b2  = (const float*)d_in[8];
  const float* g2  = (const float*)d_in[9];
  const float* be2 = (const float*)d_in[10];
  const float* m2  = (const float*)d_in[11];
  const float* v2  = (const float*)d_in[12];
  const float* w3  = (const float*)d_in[13];
  const float* b3  = (const float*)d_in[14];
  const float* g3  = (const float*)d_in[15];
  const float* be3 = (const float*)d_in[16];
  const float* m3  = (const float*)d_in[17];
  const float* v3  = (const float*)d_in[18];
  float* out = (float*)d_out;

  uint8_t* ws = (uint8_t*)d_ws;
  u16* xb    = (u16*)(ws);                      // 25,690,112 B
  u16* act1p = (u16*)(ws + 25690112ull);        // 8,388,608 B
  u16* act2  = (u16*)(ws + 34078720ull);        // 6,422,528 B
  u16* w1q   = (u16*)(ws + 40501248ull);        // 524,288 B
  u16* w2q   = (u16*)(ws + 41025536ull);        // 1,179,648 B
  u16* w3q   = (u16*)(ws + 42205184ull);        // 524,288 B
  float* a1c = (float*)(ws + 42729472ull);
  float* b1c = a1c + 256;
  float* a2c = b1c + 256;
  float* b2c = a2c + 256;
  float* a3c = b2c + 256;
  float* b3c = a3c + 1024;

  hipMemsetAsync(act1p, 0, 8388608ull, stream);

  transpose_cast_kernel<<<dim3(64, 16), 256, 0, stream>>>(x, xb);
  quant_kernel<1024, 0><<<64, 256, 0, stream>>>(w1, b1, g1, be1, m1, v1, w1q, a1c, b1c);
  quant_kernel<2304, 1><<<64, 256, 0, stream>>>(w2, b2, g2, be2, m2, v2, w2q, a2c, b2c);
  quant_kernel<256, 0><<<256, 256, 0, stream>>>(w3, b3, g3, be3, m3, v3, w3q, a3c, b3c);

  gemm_kernel<1, 1024, 64><<<dim3(196, 2), 256, 0, stream>>>(w1q, xb, a1c, b1c, act1p, (float*)nullptr, (const float*)nullptr);
  gemm_kernel<2, 2304, 64><<<dim3(196, 2), 256, 0, stream>>>(w2q, act1p, a2c, b2c, act2, (float*)nullptr, (const float*)nullptr);
  gemm_kernel<3, 256, 128><<<dim3(98, 8), 256, 0, stream>>>(w3q, act2, a3c, b3c, (u16*)nullptr, out, x);
}

// Round 4
// 239.543 us; speedup vs baseline: 1.1775x; 1.1775x over previous
//
#include <hip/hip_runtime.h>
#include <cstdint>
#include <cstddef>

typedef unsigned short u16;
typedef unsigned int u32;
typedef __attribute__((ext_vector_type(4))) float f32x4;
typedef __attribute__((ext_vector_type(8))) short s16x8;

__device__ __forceinline__ u16 f2bf(float f) {
  u32 u = __float_as_uint(f);
  u = (u + 0x7fffu + ((u >> 16) & 1u)) >> 16;
  return (u16)u;
}

__device__ __forceinline__ float silu_f(float y) {
  return y / (1.0f + __expf(-y));
}

// async global -> LDS, 16 bytes per lane, LDS dest = wave-uniform base + lane*16
__device__ __forceinline__ void gl_lds16(const u16* g, u16* l) {
  __builtin_amdgcn_global_load_lds(
      (const __attribute__((address_space(1))) void*)g,
      (__attribute__((address_space(3))) void*)l, 16, 0, 0);
}

// ---------------------------------------------------------------------------
// Weight quantization: ONE 64-thread block per output channel.
// Exact median of |w| via 8-bit radix select on abs bit pattern.
// ---------------------------------------------------------------------------
template<int N, int REMAP>
__global__ __launch_bounds__(64) void quant_kernel(
    const float* __restrict__ w, const float* __restrict__ bias,
    const float* __restrict__ g, const float* __restrict__ be,
    const float* __restrict__ mu, const float* __restrict__ var,
    u16* __restrict__ wq, float* __restrict__ alpha, float* __restrict__ beta)
{
  constexpr int NV = N / 64;
  __shared__ int hist[256];

  const int lane = threadIdx.x;
  const int ch = blockIdx.x;

  u32 vals[NV];
  const float* wp = w + (size_t)ch * N;
  #pragma unroll
  for (int t = 0; t < NV; ++t)
    vals[t] = __float_as_uint(wp[lane + 64 * t]);

  const int r0 = N / 2;
  int r = r0;
  u32 prefix = 0;
  #pragma unroll
  for (int pass = 0; pass < 4; ++pass) {
    const int shift = 24 - 8 * pass;
    hist[lane] = 0;
    hist[64 + lane] = 0;
    hist[128 + lane] = 0;
    hist[192 + lane] = 0;
    __syncthreads();
    #pragma unroll
    for (int t = 0; t < NV; ++t) {
      u32 a = vals[t] & 0x7fffffffu;
      bool cand;
      if (pass == 0) cand = true;
      else cand = ((a >> (shift + 8)) == (prefix >> (shift + 8)));
      if (cand) atomicAdd(&hist[(a >> shift) & 255], 1);
    }
    __syncthreads();
    int h0 = hist[4 * lane + 0];
    int h1 = hist[4 * lane + 1];
    int h2 = hist[4 * lane + 2];
    int h3 = hist[4 * lane + 3];
    int s4 = h0 + h1 + h2 + h3;
    int cum = s4;
    #pragma unroll
    for (int off = 1; off < 64; off <<= 1) {
      int tt = __shfl_up(cum, off);
      if (lane >= off) cum += tt;
    }
    int pre = cum - s4;
    bool sel = (r > pre) && (r <= cum);
    unsigned long long bal = __ballot(sel);
    int src = __ffsll((unsigned long long)bal) - 1;
    int c0 = pre + h0, c1 = c0 + h1, c2 = c1 + h2;
    int d_l, nr_l;
    if (r <= c0)      { d_l = 4 * lane + 0; nr_l = r - pre; }
    else if (r <= c1) { d_l = 4 * lane + 1; nr_l = r - c0; }
    else if (r <= c2) { d_l = 4 * lane + 2; nr_l = r - c1; }
    else              { d_l = 4 * lane + 3; nr_l = r - c2; }
    int d = __shfl(d_l, src);
    r = __shfl(nr_l, src);
    prefix |= (u32)d << shift;
    __syncthreads();
  }
  const u32 v0 = prefix;

  int cle = 0;
  u32 mn = 0xFFFFFFFFu;
  #pragma unroll
  for (int t = 0; t < NV; ++t) {
    u32 a = vals[t] & 0x7fffffffu;
    cle += (a <= v0) ? 1 : 0;
    if (a > v0) mn = min(mn, a);
  }
  #pragma unroll
  for (int off = 1; off < 64; off <<= 1) {
    cle += __shfl_xor(cle, off);
    mn = min(mn, (u32)__shfl_xor((int)mn, off));
  }
  u32 v1 = (cle >= r0 + 1) ? v0 : mn;

  float s = 0.5f * (__uint_as_float(v0) + __uint_as_float(v1));
  s = fmaxf(s, 1e-8f);

  #pragma unroll
  for (int t = 0; t < NV; ++t) {
    int i = lane + 64 * t;
    float q = rintf(__uint_as_float(vals[t]) / s);
    q = fminf(fmaxf(q, -1.0f), 1.0f);
    int oi;
    if (REMAP) {
      int cin = i / 9, tap = i - cin * 9;
      oi = tap * 256 + cin;
    } else {
      oi = i;
    }
    wq[(size_t)ch * N + oi] = f2bf(q);
  }
  if (lane == 0) {
    float sc = g[ch] / sqrtf(var[ch] + 1e-5f);
    alpha[ch] = s * sc;
    beta[ch] = (bias[ch] - mu[ch]) * sc + be[ch];
  }
}

// ---------------------------------------------------------------------------
// x (NCHW fp32) -> xb (NHWC bf16): [64][196][1024]
// float4 global reads; paired-u32 global stores; LDS stride 198 (2-way free).
// ---------------------------------------------------------------------------
__global__ __launch_bounds__(256) void transpose_cast_kernel(
    const float* __restrict__ x, u16* __restrict__ xb)
{
  __shared__ u16 tile[64 * 198];
  const int n = blockIdx.x;
  const int c0 = blockIdx.y * 64;
  const float* xp = x + ((size_t)n * 1024 + c0) * 196;
  const float4* xp4 = reinterpret_cast<const float4*>(xp);
  for (int i = threadIdx.x; i < 64 * 49; i += 256) {
    int c = i / 49, hg = i - c * 49;
    float4 v = xp4[i];
    u16* t = &tile[c * 198 + hg * 4];
    t[0] = f2bf(v.x); t[1] = f2bf(v.y); t[2] = f2bf(v.z); t[3] = f2bf(v.w);
  }
  __syncthreads();
  u32* op = reinterpret_cast<u32*>(xb + (size_t)n * 196 * 1024 + c0);
  for (int i = threadIdx.x; i < 196 * 32; i += 256) {
    int hw = i >> 5, cp = i & 31;
    u32 lo = tile[(cp * 2) * 198 + hw];
    u32 hi = tile[(cp * 2 + 1) * 198 + hw];
    op[hw * 512 + cp] = lo | (hi << 16);
  }
}

// ---------------------------------------------------------------------------
// GEMM: C[c][j] = sum_k W[c][k] * Act[j][k]. Tile: 128 channels x BJ pos,
// BK=64, mfma_f32_16x16x32_bf16, K-major operands, XOR-swizzled LDS.
// Staging is ASYNC global_load_lds (16B/lane); the XOR swizzle is applied on
// the SOURCE address (lane l loads global chunk (l&7)^(l>>3) of its row), so
// LDS chunk p of row r holds global chunk p^(r&7) — identical layout to the
// verified register-staged version; fragment reads unchanged, 0 conflicts.
// MODE 1: B = xb flat; store silu(bn) bf16 into padded act1p  (BJ=64)
// MODE 2: B gathered from act1p (implicit 3x3); store bf16 act2 (BJ=64)
// MODE 3: B = act2 flat; coalesced fp32 NCHW epilogue via LDS    (BJ=128)
// ---------------------------------------------------------------------------
template<int MODE, int KTOT, int BJ>
__global__ __launch_bounds__(256, 2) void gemm_kernel(
    const u16* __restrict__ Wq, const u16* __restrict__ Bact,
    const float* __restrict__ alpha, const float* __restrict__ beta,
    u16* __restrict__ outb, float* __restrict__ outf, const float* __restrict__ xres)
{
  constexpr int BK = 64;
  constexpr int NKT = KTOT / BK;
  constexpr int NI = BJ / 32;          // n-fragments per wave
  constexpr int ACH = 4;               // A chunks (1KB) per wave: 16KB/4/1KB
  constexpr int BCH = BJ / 32;         // B chunks per wave
  constexpr int SMEM_SIZE = (MODE == 3) ? 34816 : 25600;

  __shared__ __align__(16) char smem[SMEM_SIZE];
  u16* As = (u16*)smem;                                   // 128 x 64
  u16* Bs = (u16*)(smem + 16384);                         // BJ x 64
  float* aS = (float*)(MODE == 3 ? (smem + 33792) : (smem + 16384 + BJ * 128));
  float* bS = aS + 128;
  float* lbuf = (float*)smem;                             // MODE 3 epilogue, 64 x 132

  const int tid = threadIdx.x;
  const int jb = blockIdx.x * BJ;
  const int cb = blockIdx.y * 128;
  const int wave = tid >> 6;
  const int lane = tid & 63;
  const int wm = (wave & 1) * 64;
  const int wn = (wave >> 1) * (BJ / 2);
  const int quad = lane >> 4;
  const int l16 = lane & 15;
  const int lr = lane >> 3;            // row-in-chunk 0..7
  const int perm = (lane & 7) ^ lr;    // XOR-inverse source chunk

  // per-lane async-staging source pointers (constant across K-loop)
  const u16* gA[ACH];
  #pragma unroll
  for (int it = 0; it < ACH; ++it) {
    int row = wave * 32 + it * 8 + lr;
    gA[it] = Wq + (size_t)(cb + row) * KTOT + perm * 8;
  }
  const u16* gB[BCH];
  #pragma unroll
  for (int it = 0; it < BCH; ++it) {
    int row = wave * (8 * BCH) + it * 8 + lr;
    if (MODE == 2) {
      int j = jb + row;
      int n = j / 196, hw = j - n * 196;
      int h = hw / 14, w = hw - h * 14;
      gB[it] = Bact + (size_t)(((n * 16 + h) * 16 + w) * 256) + perm * 8;
    } else {
      gB[it] = Bact + (size_t)(jb + row) * KTOT + perm * 8;
    }
  }

  if (tid < 128) {
    aS[tid] = alpha[cb + tid];
    bS[tid] = beta[cb + tid];
  }

  f32x4 acc[4][NI];
  #pragma unroll
  for (int a = 0; a < 4; ++a)
    #pragma unroll
    for (int b = 0; b < NI; ++b)
      acc[a][b] = {0.f, 0.f, 0.f, 0.f};

  for (int kt = 0; kt < NKT; ++kt) {
    #pragma unroll
    for (int it = 0; it < ACH; ++it)
      gl_lds16(gA[it] + kt * BK, As + (wave * ACH + it) * 512);
    if (MODE == 2) {
      int tap = kt >> 2;
      int c0 = (kt & 3) * 64;
      int dy = tap / 3, dx = tap - dy * 3;
      int tapoff = (dy * 16 + dx) * 256 + c0;
      #pragma unroll
      for (int it = 0; it < BCH; ++it)
        gl_lds16(gB[it] + tapoff, Bs + (wave * BCH + it) * 512);
    } else {
      #pragma unroll
      for (int it = 0; it < BCH; ++it)
        gl_lds16(gB[it] + kt * BK, Bs + (wave * BCH + it) * 512);
    }
    __syncthreads();

    #pragma unroll
    for (int s = 0; s < 2; ++s) {
      s16x8 af[4], bf[NI];
      #pragma unroll
      for (int mi = 0; mi < 4; ++mi) {
        int row = wm + mi * 16 + l16;
        int kc = s * 4 + quad;
        af[mi] = *reinterpret_cast<const s16x8*>(&As[row * BK + ((kc ^ (row & 7)) << 3)]);
      }
      #pragma unroll
      for (int ni = 0; ni < NI; ++ni) {
        int row = wn + ni * 16 + l16;
        int kc = s * 4 + quad;
        bf[ni] = *reinterpret_cast<const s16x8*>(&Bs[row * BK + ((kc ^ (row & 7)) << 3)]);
      }
      #pragma unroll
      for (int mi = 0; mi < 4; ++mi)
        #pragma unroll
        for (int ni = 0; ni < NI; ++ni)
          acc[mi][ni] = __builtin_amdgcn_mfma_f32_16x16x32_bf16(af[mi], bf[ni], acc[mi][ni], 0, 0, 0);
    }
    __syncthreads();
  }

  // Epilogue. D layout: row(channel) = quad*4 + reg, col(j) = lane&15.
  if (MODE == 1 || MODE == 2) {
    #pragma unroll
    for (int mi = 0; mi < 4; ++mi) {
      const int lc = wm + mi * 16 + quad * 4;
      #pragma unroll
      for (int ni = 0; ni < NI; ++ni) {
        const int j = jb + wn + ni * 16 + l16;
        ushort4 pk;
        float y;
        y = silu_f(aS[lc + 0] * acc[mi][ni][0] + bS[lc + 0]); pk.x = f2bf(y);
        y = silu_f(aS[lc + 1] * acc[mi][ni][1] + bS[lc + 1]); pk.y = f2bf(y);
        y = silu_f(aS[lc + 2] * acc[mi][ni][2] + bS[lc + 2]); pk.z = f2bf(y);
        y = silu_f(aS[lc + 3] * acc[mi][ni][3] + bS[lc + 3]); pk.w = f2bf(y);
        size_t base;
        if (MODE == 1) {
          int n = j / 196, hw = j - n * 196;
          int h = hw / 14, w = hw - h * 14;
          base = (size_t)(((n * 16 + h + 1) * 16) + (w + 1)) * 256 + cb + lc;
        } else {
          base = (size_t)j * 256 + cb + lc;
        }
        *reinterpret_cast<ushort4*>(&outb[base]) = pk;
      }
    }
  } else {
    // MODE 3: two 64-channel chunks through LDS, fully coalesced fp32 out.
    #pragma unroll
    for (int k = 0; k < 2; ++k) {
      if ((wave & 1) == k) {
        #pragma unroll
        for (int mi = 0; mi < 4; ++mi) {
          const int cl = mi * 16 + quad * 4;
          const int gc = 64 * k + cl;
          #pragma unroll
          for (int ni = 0; ni < 4; ++ni) {
            const int jj = wn + ni * 16 + l16;
            #pragma unroll
            for (int r = 0; r < 4; ++r)
              lbuf[(cl + r) * 132 + jj] = aS[gc + r] * acc[mi][ni][r] + bS[gc + r];
          }
        }
      }
      __syncthreads();
      #pragma unroll
      for (int it = 0; it < 8; ++it) {
        int idx = tid + it * 256;
        int cl = idx >> 5;
        int jg = idx & 31;
        int c = cb + 64 * k + cl;
        int j0 = jb + jg * 4;
        int n = j0 / 196, hw = j0 - n * 196;
        size_t o = (size_t)n * 200704 + (size_t)c * 196 + hw;
        float4 lv = *reinterpret_cast<float4*>(&lbuf[cl * 132 + jg * 4]);
        float4 xv = *reinterpret_cast<const float4*>(&xres[o]);
        float4 ov;
        ov.x = silu_f(lv.x + xv.x);
        ov.y = silu_f(lv.y + xv.y);
        ov.z = silu_f(lv.z + xv.z);
        ov.w = silu_f(lv.w + xv.w);
        *reinterpret_cast<float4*>(&outf[o]) = ov;
      }
      __syncthreads();
    }
  }
}

// ---------------------------------------------------------------------------
extern "C" void kernel_launch(void* const* d_in, const int* in_sizes, int n_in,
                              void* d_out, int out_size, void* d_ws, size_t ws_size,
                              hipStream_t stream)
{
  const float* x   = (const float*)d_in[0];
  const float* w1  = (const float*)d_in[1];
  const float* b1  = (const float*)d_in[2];
  const float* g1  = (const float*)d_in[3];
  const float* be1 = (const float*)d_in[4];
  const float* m1  = (const float*)d_in[5];
  const float* v1  = (const float*)d_in[6];
  const float* w2  = (const float*)d_in[7];
  const float* b2  = (const float*)d_in[8];
  const float* g2  = (const float*)d_in[9];
  const float* be2 = (const float*)d_in[10];
  const float* m2  = (const float*)d_in[11];
  const float* v2  = (const float*)d_in[12];
  const float* w3  = (const float*)d_in[13];
  const float* b3  = (const float*)d_in[14];
  const float* g3  = (const float*)d_in[15];
  const float* be3 = (const float*)d_in[16];
  const float* m3  = (const float*)d_in[17];
  const float* v3  = (const float*)d_in[18];
  float* out = (float*)d_out;

  uint8_t* ws = (uint8_t*)d_ws;
  u16* xb    = (u16*)(ws);                      // 25,690,112 B
  u16* act1p = (u16*)(ws + 25690112ull);        // 8,388,608 B
  u16* act2  = (u16*)(ws + 34078720ull);        // 6,422,528 B
  u16* w1q   = (u16*)(ws + 40501248ull);        // 524,288 B
  u16* w2q   = (u16*)(ws + 41025536ull);        // 1,179,648 B
  u16* w3q   = (u16*)(ws + 42205184ull);        // 524,288 B
  float* a1c = (float*)(ws + 42729472ull);
  float* b1c = a1c + 256;
  float* a2c = b1c + 256;
  float* b2c = a2c + 256;
  float* a3c = b2c + 256;
  float* b3c = a3c + 1024;

  hipMemsetAsync(act1p, 0, 8388608ull, stream);

  transpose_cast_kernel<<<dim3(64, 16), 256, 0, stream>>>(x, xb);
  quant_kernel<1024, 0><<<256, 64, 0, stream>>>(w1, b1, g1, be1, m1, v1, w1q, a1c, b1c);
  quant_kernel<2304, 1><<<256, 64, 0, stream>>>(w2, b2, g2, be2, m2, v2, w2q, a2c, b2c);
  quant_kernel<256, 0><<<1024, 64, 0, stream>>>(w3, b3, g3, be3, m3, v3, w3q, a3c, b3c);

  gemm_kernel<1, 1024, 64><<<dim3(196, 2), 256, 0, stream>>>(w1q, xb, a1c, b1c, act1p, (float*)nullptr, (const float*)nullptr);
  gemm_kernel<2, 2304, 64><<<dim3(196, 2), 256, 0, stream>>>(w2q, act1p, a2c, b2c, act2, (float*)nullptr, (const float*)nullptr);
  gemm_kernel<3, 256, 128><<<dim3(98, 8), 256, 0, stream>>>(w3q, act2, a3c, b3c, (u16*)nullptr, out, x);
}

// Round 5
// 227.435 us; speedup vs baseline: 1.2402x; 1.0532x over previous
//
#include <hip/hip_runtime.h>
#include <cstdint>
#include <cstddef>

typedef unsigned short u16;
typedef unsigned int u32;
typedef __attribute__((ext_vector_type(4))) float f32x4;
typedef __attribute__((ext_vector_type(8))) short s16x8;

__device__ __forceinline__ u16 f2bf(float f) {
  u32 u = __float_as_uint(f);
  u = (u + 0x7fffu + ((u >> 16) & 1u)) >> 16;
  return (u16)u;
}

__device__ __forceinline__ float silu_f(float y) {
  return y / (1.0f + __expf(-y));
}

// async global -> LDS, 16 bytes per lane, LDS dest = wave-uniform base + lane*16
__device__ __forceinline__ void gl_lds16(const u16* g, u16* l) {
  __builtin_amdgcn_global_load_lds(
      (const __attribute__((address_space(1))) void*)g,
      (__attribute__((address_space(3))) void*)l, 16, 0, 0);
}

// ---------------------------------------------------------------------------
// Quant device fn: ONE WAVE per output channel (4 channels per 256-thr block).
// Exact median of |w| via 8-bit radix select on abs bit pattern.
// ---------------------------------------------------------------------------
template<int N, int REMAP>
__device__ void quant_dev(
    int grp, int wave, int lane, int* hist /* 4*256 ints in LDS */,
    const float* __restrict__ w, const float* __restrict__ bias,
    const float* __restrict__ g, const float* __restrict__ be,
    const float* __restrict__ mu, const float* __restrict__ var,
    u16* __restrict__ wq, float* __restrict__ alpha, float* __restrict__ beta)
{
  constexpr int NV = N / 64;
  const int ch = grp * 4 + wave;
  const int wb = wave * 256;

  u32 vals[NV];
  const float* wp = w + (size_t)ch * N;
  #pragma unroll
  for (int t = 0; t < NV; ++t)
    vals[t] = __float_as_uint(wp[lane + 64 * t]);

  const int r0 = N / 2;
  int r = r0;
  u32 prefix = 0;
  #pragma unroll
  for (int pass = 0; pass < 4; ++pass) {
    const int shift = 24 - 8 * pass;
    hist[wb + lane] = 0;
    hist[wb + 64 + lane] = 0;
    hist[wb + 128 + lane] = 0;
    hist[wb + 192 + lane] = 0;
    __syncthreads();
    #pragma unroll
    for (int t = 0; t < NV; ++t) {
      u32 a = vals[t] & 0x7fffffffu;
      bool cand;
      if (pass == 0) cand = true;
      else cand = ((a >> (shift + 8)) == (prefix >> (shift + 8)));
      if (cand) atomicAdd(&hist[wb + ((a >> shift) & 255)], 1);
    }
    __syncthreads();
    int h0 = hist[wb + 4 * lane + 0];
    int h1 = hist[wb + 4 * lane + 1];
    int h2 = hist[wb + 4 * lane + 2];
    int h3 = hist[wb + 4 * lane + 3];
    int s4 = h0 + h1 + h2 + h3;
    int cum = s4;
    #pragma unroll
    for (int off = 1; off < 64; off <<= 1) {
      int tt = __shfl_up(cum, off);
      if (lane >= off) cum += tt;
    }
    int pre = cum - s4;
    bool sel = (r > pre) && (r <= cum);
    unsigned long long bal = __ballot(sel);
    int src = __ffsll((unsigned long long)bal) - 1;
    int c0 = pre + h0, c1 = c0 + h1, c2 = c1 + h2;
    int d_l, nr_l;
    if (r <= c0)      { d_l = 4 * lane + 0; nr_l = r - pre; }
    else if (r <= c1) { d_l = 4 * lane + 1; nr_l = r - c0; }
    else if (r <= c2) { d_l = 4 * lane + 2; nr_l = r - c1; }
    else              { d_l = 4 * lane + 3; nr_l = r - c2; }
    int d = __shfl(d_l, src);
    r = __shfl(nr_l, src);
    prefix |= (u32)d << shift;
    __syncthreads();
  }
  const u32 v0 = prefix;

  int cle = 0;
  u32 mn = 0xFFFFFFFFu;
  #pragma unroll
  for (int t = 0; t < NV; ++t) {
    u32 a = vals[t] & 0x7fffffffu;
    cle += (a <= v0) ? 1 : 0;
    if (a > v0) mn = min(mn, a);
  }
  #pragma unroll
  for (int off = 1; off < 64; off <<= 1) {
    cle += __shfl_xor(cle, off);
    mn = min(mn, (u32)__shfl_xor((int)mn, off));
  }
  u32 v1 = (cle >= r0 + 1) ? v0 : mn;

  float s = 0.5f * (__uint_as_float(v0) + __uint_as_float(v1));
  s = fmaxf(s, 1e-8f);

  #pragma unroll
  for (int t = 0; t < NV; ++t) {
    int i = lane + 64 * t;
    float q = rintf(__uint_as_float(vals[t]) / s);
    q = fminf(fmaxf(q, -1.0f), 1.0f);
    int oi;
    if (REMAP) {
      int cin = i / 9, tap = i - cin * 9;
      oi = tap * 256 + cin;
    } else {
      oi = i;
    }
    wq[(size_t)ch * N + oi] = f2bf(q);
  }
  if (lane == 0) {
    float sc = g[ch] / sqrtf(var[ch] + 1e-5f);
    alpha[ch] = s * sc;
    beta[ch] = (bias[ch] - mu[ch]) * sc + be[ch];
  }
}

// ---------------------------------------------------------------------------
// Fused prep kernel, dispatch by blockIdx range:
//   [0,1024)    : transpose x (NCHW fp32) -> xb (NHWC bf16)
//   [1024,1088) : quant w1 (N=1024)
//   [1088,1152) : quant w2 (N=2304, REMAP)
//   [1152,1408) : quant w3 (N=256)
//   [1408,1472) : zero act1p halo (60 border positions x 256 ch per image)
// ---------------------------------------------------------------------------
__global__ __launch_bounds__(256) void prep_kernel(
    const float* __restrict__ x, u16* __restrict__ xb,
    const float* __restrict__ w1, const float* __restrict__ b1,
    const float* __restrict__ g1, const float* __restrict__ be1,
    const float* __restrict__ m1, const float* __restrict__ v1,
    u16* __restrict__ w1q, float* __restrict__ a1c, float* __restrict__ b1c,
    const float* __restrict__ w2, const float* __restrict__ b2,
    const float* __restrict__ g2, const float* __restrict__ be2,
    const float* __restrict__ m2, const float* __restrict__ v2,
    u16* __restrict__ w2q, float* __restrict__ a2c, float* __restrict__ b2c,
    const float* __restrict__ w3, const float* __restrict__ b3,
    const float* __restrict__ g3, const float* __restrict__ be3,
    const float* __restrict__ m3, const float* __restrict__ v3,
    u16* __restrict__ w3q, float* __restrict__ a3c, float* __restrict__ b3c,
    u16* __restrict__ act1p)
{
  __shared__ __align__(16) char smem[25344];
  const int b = blockIdx.x;
  const int tid = threadIdx.x;
  const int wave = tid >> 6;
  const int lane = tid & 63;

  if (b < 1024) {
    // transpose: n = b>>4, c0 = (b&15)*64
    u16* tile = (u16*)smem;                 // 64 x 198
    const int n = b >> 4;
    const int c0 = (b & 15) * 64;
    const float* xp = x + ((size_t)n * 1024 + c0) * 196;
    const float4* xp4 = reinterpret_cast<const float4*>(xp);
    for (int i = tid; i < 64 * 49; i += 256) {
      int c = i / 49, hg = i - c * 49;
      float4 v = xp4[i];
      u16* t = &tile[c * 198 + hg * 4];
      t[0] = f2bf(v.x); t[1] = f2bf(v.y); t[2] = f2bf(v.z); t[3] = f2bf(v.w);
    }
    __syncthreads();
    u32* op = reinterpret_cast<u32*>(xb + (size_t)n * 196 * 1024 + c0);
    for (int i = tid; i < 196 * 32; i += 256) {
      int hw = i >> 5, cp = i & 31;
      u32 lo = tile[(cp * 2) * 198 + hw];
      u32 hi = tile[(cp * 2 + 1) * 198 + hw];
      op[hw * 512 + cp] = lo | (hi << 16);
    }
  } else if (b < 1088) {
    quant_dev<1024, 0>(b - 1024, wave, lane, (int*)smem,
                       w1, b1, g1, be1, m1, v1, w1q, a1c, b1c);
  } else if (b < 1152) {
    quant_dev<2304, 1>(b - 1088, wave, lane, (int*)smem,
                       w2, b2, g2, be2, m2, v2, w2q, a2c, b2c);
  } else if (b < 1408) {
    quant_dev<256, 0>(b - 1152, wave, lane, (int*)smem,
                      w3, b3, g3, be3, m3, v3, w3q, a3c, b3c);
  } else {
    // act1p halo zero: image n = b - 1408
    const int n = b - 1408;
    u32* base = reinterpret_cast<u32*>(act1p + (size_t)n * 16 * 16 * 256);
    for (int i = tid; i < 7680; i += 256) {
      int p = i >> 7;        // 0..59 halo position
      int cc = i & 127;      // u32 channel pair
      int h, w;
      if (p < 16)      { h = 0;  w = p; }
      else if (p < 32) { h = 15; w = p - 16; }
      else { int q = p - 32; h = 1 + (q >> 1); w = (q & 1) * 15; }
      base[((h * 16 + w) << 7) + cc] = 0u;
    }
  }
}

// ---------------------------------------------------------------------------
// GEMM: C[c][j] = sum_k W[c][k] * Act[j][k]. Tile: 128 channels x BJ pos,
// BK=64, mfma_f32_16x16x32_bf16, K-major operands, XOR-swizzled LDS.
// Async global_load_lds staging (16B/lane), XOR swizzle applied on the
// SOURCE address so the LDS layout matches the verified register-staged one.
// MODE 1: B = xb flat; store silu(bn) bf16 into padded act1p  (BJ=32)
// MODE 2: B gathered from act1p (implicit 3x3); store bf16 act2 (BJ=32)
// MODE 3: B = act2 flat; coalesced fp32 NCHW epilogue via LDS    (BJ=128)
// ---------------------------------------------------------------------------
template<int MODE, int KTOT, int BJ>
__global__ __launch_bounds__(256, 4) void gemm_kernel(
    const u16* __restrict__ Wq, const u16* __restrict__ Bact,
    const float* __restrict__ alpha, const float* __restrict__ beta,
    u16* __restrict__ outb, float* __restrict__ outf, const float* __restrict__ xres)
{
  constexpr int BK = 64;
  constexpr int NKT = KTOT / BK;
  constexpr int NI = BJ / 32;          // n-fragments per wave
  constexpr int ACH = 4;               // A chunks (1KB) per wave
  constexpr int BCH = BJ / 32;         // B chunks per wave
  constexpr int SMEM_SIZE = (MODE == 3) ? 34816 : (16384 + BJ * 128 + 1024);

  __shared__ __align__(16) char smem[SMEM_SIZE];
  u16* As = (u16*)smem;                                   // 128 x 64
  u16* Bs = (u16*)(smem + 16384);                         // BJ x 64
  float* aS = (float*)(MODE == 3 ? (smem + 33792) : (smem + 16384 + BJ * 128));
  float* bS = aS + 128;
  float* lbuf = (float*)smem;                             // MODE 3 epilogue, 64 x 132

  const int tid = threadIdx.x;
  const int jb = blockIdx.x * BJ;
  const int cb = blockIdx.y * 128;
  const int wave = tid >> 6;
  const int lane = tid & 63;
  const int wm = (wave & 1) * 64;
  const int wn = (wave >> 1) * (BJ / 2);
  const int quad = lane >> 4;
  const int l16 = lane & 15;
  const int lr = lane >> 3;            // row-in-chunk 0..7
  const int perm = (lane & 7) ^ lr;    // XOR-inverse source chunk

  // per-lane async-staging source pointers (constant across K-loop)
  const u16* gA[ACH];
  #pragma unroll
  for (int it = 0; it < ACH; ++it) {
    int row = wave * 32 + it * 8 + lr;
    gA[it] = Wq + (size_t)(cb + row) * KTOT + perm * 8;
  }
  const u16* gB[BCH];
  #pragma unroll
  for (int it = 0; it < BCH; ++it) {
    int row = wave * (8 * BCH) + it * 8 + lr;
    if (MODE == 2) {
      int j = jb + row;
      int n = j / 196, hw = j - n * 196;
      int h = hw / 14, w = hw - h * 14;
      gB[it] = Bact + (size_t)(((n * 16 + h) * 16 + w) * 256) + perm * 8;
    } else {
      gB[it] = Bact + (size_t)(jb + row) * KTOT + perm * 8;
    }
  }

  if (tid < 128) {
    aS[tid] = alpha[cb + tid];
    bS[tid] = beta[cb + tid];
  }

  f32x4 acc[4][NI];
  #pragma unroll
  for (int a = 0; a < 4; ++a)
    #pragma unroll
    for (int b = 0; b < NI; ++b)
      acc[a][b] = {0.f, 0.f, 0.f, 0.f};

  for (int kt = 0; kt < NKT; ++kt) {
    #pragma unroll
    for (int it = 0; it < ACH; ++it)
      gl_lds16(gA[it] + kt * BK, As + (wave * ACH + it) * 512);
    if (MODE == 2) {
      int tap = kt >> 2;
      int c0 = (kt & 3) * 64;
      int dy = tap / 3, dx = tap - dy * 3;
      int tapoff = (dy * 16 + dx) * 256 + c0;
      #pragma unroll
      for (int it = 0; it < BCH; ++it)
        gl_lds16(gB[it] + tapoff, Bs + (wave * BCH + it) * 512);
    } else {
      #pragma unroll
      for (int it = 0; it < BCH; ++it)
        gl_lds16(gB[it] + kt * BK, Bs + (wave * BCH + it) * 512);
    }
    __syncthreads();

    #pragma unroll
    for (int s = 0; s < 2; ++s) {
      s16x8 af[4], bf[NI];
      #pragma unroll
      for (int mi = 0; mi < 4; ++mi) {
        int row = wm + mi * 16 + l16;
        int kc = s * 4 + quad;
        af[mi] = *reinterpret_cast<const s16x8*>(&As[row * BK + ((kc ^ (row & 7)) << 3)]);
      }
      #pragma unroll
      for (int ni = 0; ni < NI; ++ni) {
        int row = wn + ni * 16 + l16;
        int kc = s * 4 + quad;
        bf[ni] = *reinterpret_cast<const s16x8*>(&Bs[row * BK + ((kc ^ (row & 7)) << 3)]);
      }
      #pragma unroll
      for (int mi = 0; mi < 4; ++mi)
        #pragma unroll
        for (int ni = 0; ni < NI; ++ni)
          acc[mi][ni] = __builtin_amdgcn_mfma_f32_16x16x32_bf16(af[mi], bf[ni], acc[mi][ni], 0, 0, 0);
    }
    __syncthreads();
  }

  // Epilogue. D layout: row(channel) = quad*4 + reg, col(j) = lane&15.
  if (MODE == 1 || MODE == 2) {
    #pragma unroll
    for (int mi = 0; mi < 4; ++mi) {
      const int lc = wm + mi * 16 + quad * 4;
      #pragma unroll
      for (int ni = 0; ni < NI; ++ni) {
        const int j = jb + wn + ni * 16 + l16;
        ushort4 pk;
        float y;
        y = silu_f(aS[lc + 0] * acc[mi][ni][0] + bS[lc + 0]); pk.x = f2bf(y);
        y = silu_f(aS[lc + 1] * acc[mi][ni][1] + bS[lc + 1]); pk.y = f2bf(y);
        y = silu_f(aS[lc + 2] * acc[mi][ni][2] + bS[lc + 2]); pk.z = f2bf(y);
        y = silu_f(aS[lc + 3] * acc[mi][ni][3] + bS[lc + 3]); pk.w = f2bf(y);
        size_t base;
        if (MODE == 1) {
          int n = j / 196, hw = j - n * 196;
          int h = hw / 14, w = hw - h * 14;
          base = (size_t)(((n * 16 + h + 1) * 16) + (w + 1)) * 256 + cb + lc;
        } else {
          base = (size_t)j * 256 + cb + lc;
        }
        *reinterpret_cast<ushort4*>(&outb[base]) = pk;
      }
    }
  } else {
    // MODE 3: two 64-channel chunks through LDS, fully coalesced fp32 out.
    #pragma unroll
    for (int k = 0; k < 2; ++k) {
      if ((wave & 1) == k) {
        #pragma unroll
        for (int mi = 0; mi < 4; ++mi) {
          const int cl = mi * 16 + quad * 4;
          const int gc = 64 * k + cl;
          #pragma unroll
          for (int ni = 0; ni < 4; ++ni) {
            const int jj = wn + ni * 16 + l16;
            #pragma unroll
            for (int r = 0; r < 4; ++r)
              lbuf[(cl + r) * 132 + jj] = aS[gc + r] * acc[mi][ni][r] + bS[gc + r];
          }
        }
      }
      __syncthreads();
      #pragma unroll
      for (int it = 0; it < 8; ++it) {
        int idx = tid + it * 256;
        int cl = idx >> 5;
        int jg = idx & 31;
        int c = cb + 64 * k + cl;
        int j0 = jb + jg * 4;
        int n = j0 / 196, hw = j0 - n * 196;
        size_t o = (size_t)n * 200704 + (size_t)c * 196 + hw;
        float4 lv = *reinterpret_cast<float4*>(&lbuf[cl * 132 + jg * 4]);
        float4 xv = *reinterpret_cast<const float4*>(&xres[o]);
        float4 ov;
        ov.x = silu_f(lv.x + xv.x);
        ov.y = silu_f(lv.y + xv.y);
        ov.z = silu_f(lv.z + xv.z);
        ov.w = silu_f(lv.w + xv.w);
        *reinterpret_cast<float4*>(&outf[o]) = ov;
      }
      __syncthreads();
    }
  }
}

// ---------------------------------------------------------------------------
extern "C" void kernel_launch(void* const* d_in, const int* in_sizes, int n_in,
                              void* d_out, int out_size, void* d_ws, size_t ws_size,
                              hipStream_t stream)
{
  const float* x   = (const float*)d_in[0];
  const float* w1  = (const float*)d_in[1];
  const float* b1  = (const float*)d_in[2];
  const float* g1  = (const float*)d_in[3];
  const float* be1 = (const float*)d_in[4];
  const float* m1  = (const float*)d_in[5];
  const float* v1  = (const float*)d_in[6];
  const float* w2  = (const float*)d_in[7];
  const float* b2  = (const float*)d_in[8];
  const float* g2  = (const float*)d_in[9];
  const float* be2 = (const float*)d_in[10];
  const float* m2  = (const float*)d_in[11];
  const float* v2  = (const float*)d_in[12];
  const float* w3  = (const float*)d_in[13];
  const float* b3  = (const float*)d_in[14];
  const float* g3  = (const float*)d_in[15];
  const float* be3 = (const float*)d_in[16];
  const float* m3  = (const float*)d_in[17];
  const float* v3  = (const float*)d_in[18];
  float* out = (float*)d_out;

  uint8_t* ws = (uint8_t*)d_ws;
  u16* xb    = (u16*)(ws);                      // 25,690,112 B
  u16* act1p = (u16*)(ws + 25690112ull);        // 8,388,608 B
  u16* act2  = (u16*)(ws + 34078720ull);        // 6,422,528 B
  u16* w1q   = (u16*)(ws + 40501248ull);        // 524,288 B
  u16* w2q   = (u16*)(ws + 41025536ull);        // 1,179,648 B
  u16* w3q   = (u16*)(ws + 42205184ull);        // 524,288 B
  float* a1c = (float*)(ws + 42729472ull);
  float* b1c = a1c + 256;
  float* a2c = b1c + 256;
  float* b2c = a2c + 256;
  float* a3c = b2c + 256;
  float* b3c = a3c + 1024;

  prep_kernel<<<1472, 256, 0, stream>>>(
      x, xb,
      w1, b1, g1, be1, m1, v1, w1q, a1c, b1c,
      w2, b2, g2, be2, m2, v2, w2q, a2c, b2c,
      w3, b3, g3, be3, m3, v3, w3q, a3c, b3c,
      act1p);

  gemm_kernel<1, 1024, 32><<<dim3(392, 2), 256, 0, stream>>>(w1q, xb, a1c, b1c, act1p, (float*)nullptr, (const float*)nullptr);
  gemm_kernel<2, 2304, 32><<<dim3(392, 2), 256, 0, stream>>>(w2q, act1p, a2c, b2c, act2, (float*)nullptr, (const float*)nullptr);
  gemm_kernel<3, 256, 128><<<dim3(98, 8), 256, 0, stream>>>(w3q, act2, a3c, b3c, (u16*)nullptr, out, x);
}